// Round 2
// baseline (333.500 us; speedup 1.0000x reference)
//
#include <hip/hip_runtime.h>

typedef __bf16 bf16_t;
using bf16x8 = __attribute__((ext_vector_type(8))) __bf16;
using bf16x4 = __attribute__((ext_vector_type(4))) __bf16;
using f32x4  = __attribute__((ext_vector_type(4))) float;

#define B_   4
#define S_   2048
#define D_   1024
#define H_   16
#define DK_  64
#define SQKV 3072   // QKV buffer row stride (Q|K|V concatenated)

__device__ __forceinline__ void gload_lds16(const void* g, void* l) {
  __builtin_amdgcn_global_load_lds((const __attribute__((address_space(1))) void*)g,
                                   (__attribute__((address_space(3))) void*)l, 16, 0, 0);
}

// ---------------- fp32 -> bf16 cast (vectorized) ----------------
__global__ void cast_f32_to_bf16(const float* __restrict__ in, bf16_t* __restrict__ out, int n4) {
  int i = blockIdx.x * 256 + threadIdx.x;
  if (i >= n4) return;
  float4 v = reinterpret_cast<const float4*>(in)[i];
  bf16x4 o;
  o[0] = (bf16_t)v.x; o[1] = (bf16_t)v.y; o[2] = (bf16_t)v.z; o[3] = (bf16_t)v.w;
  reinterpret_cast<bf16x4*>(out)[i] = o;
}

// ---------------- C[M,N] = A[M,K] * B[N,K]^T  (bf16 in, OutT out) ----------------
// 128x128 tile, BK=64, 4 waves (2x2 of 64x64), global_load_lds w/ pre-swizzled src,
// XOR-swizzled ds_read_b128 (conflict-free). XCD-aware block swizzle (T1).
template <typename OutT>
__global__ void gemm_bt(const bf16_t* __restrict__ A, const bf16_t* __restrict__ Bm,
                        OutT* __restrict__ C, int M, int N, int K) {
  __shared__ alignas(16) char As[16384];
  __shared__ alignas(16) char Bs[16384];
  const int tid  = threadIdx.x;
  const int wid  = tid >> 6, lane = tid & 63;
  const int g    = lane >> 4, l15 = lane & 15;

  // XCD-aware bijective block swizzle (grids here are %8 == 0)
  int nwg = gridDim.x * gridDim.y;
  int bid = blockIdx.y * gridDim.x + blockIdx.x;
  int sb  = ((nwg & 7) == 0) ? ((bid & 7) * (nwg >> 3) + (bid >> 3)) : bid;
  int bx  = sb % gridDim.x, by = sb / gridDim.x;

  const long row0 = (long)by * 128, col0 = (long)bx * 128;
  const int wr = (wid >> 1) * 64, wc = (wid & 1) * 64;
  f32x4 acc[4][4] = {};

  for (int k0 = 0; k0 < K; k0 += 64) {
    __syncthreads();
#pragma unroll
    for (int i = 0; i < 4; ++i) {
      int L = i * 256 + tid;
      int r = L >> 3, s = L & 7;
      int sc = s ^ (r & 7);                       // inverse-swizzled global source
      const bf16_t* ga = A  + (row0 + r) * (long)K + k0 + sc * 8;
      const bf16_t* gb = Bm + (col0 + r) * (long)K + k0 + sc * 8;
      gload_lds16(ga, As + (i * 256 + wid * 64) * 16);
      gload_lds16(gb, Bs + (i * 256 + wid * 64) * 16);
    }
    __syncthreads();
#pragma unroll
    for (int kk = 0; kk < 2; ++kk) {
      bf16x8 af[4], bfr[4];
#pragma unroll
      for (int m = 0; m < 4; ++m) {
        int r = wr + m * 16 + l15;
        int s = (kk * 4 + g) ^ (r & 7);
        af[m] = *reinterpret_cast<const bf16x8*>(As + r * 128 + s * 16);
      }
#pragma unroll
      for (int n = 0; n < 4; ++n) {
        int r = wc + n * 16 + l15;
        int s = (kk * 4 + g) ^ (r & 7);
        bfr[n] = *reinterpret_cast<const bf16x8*>(Bs + r * 128 + s * 16);
      }
#pragma unroll
      for (int m = 0; m < 4; ++m)
#pragma unroll
        for (int n = 0; n < 4; ++n)
          acc[m][n] = __builtin_amdgcn_mfma_f32_16x16x32_bf16(af[m], bfr[n], acc[m][n], 0, 0, 0);
    }
  }
  // epilogue: C/D layout col=lane&15, row=(lane>>4)*4+j  [verified m89/m91]
#pragma unroll
  for (int m = 0; m < 4; ++m)
#pragma unroll
    for (int n = 0; n < 4; ++n)
#pragma unroll
      for (int j = 0; j < 4; ++j) {
        long r = row0 + wr + m * 16 + g * 4 + j;
        long c = col0 + wc + n * 16 + l15;
        C[r * (long)N + c] = (OutT)acc[m][n][j];
      }
}

// ---------------- flash attention (causal), bf16 MFMA ----------------
// grid: x = S/64 (q tile), y = B*H. 4 waves x 16 q-rows. KVBLK=64.
// XCD swizzle keeps all q-tiles of one (b,h) on one XCD (KV L2 locality);
// qt reversed so longest (causal) blocks dispatch first.
__global__ void attn_kernel(const bf16_t* __restrict__ qkv, bf16_t* __restrict__ Ob) {
  __shared__ alignas(16) char ldsK[8192];        // [64 kv][64 d] bf16, XOR-swizzled
  __shared__ alignas(16) char ldsV[9216];        // [64 d][72] bf16 (transposed, padded)
  __shared__ alignas(16) char ldsP[4][2304];     // per-wave [16 q][72] bf16
  const int tid = threadIdx.x;
  const int w   = tid >> 6, lane = tid & 63;
  const int g   = lane >> 4, l15 = lane & 15;

  int bid = blockIdx.y * 32 + blockIdx.x;        // 2048 blocks total
  int sb  = (bid & 7) * 256 + (bid >> 3);        // XCD-bijective (2048 % 8 == 0)
  const int qt = 31 - (sb & 31);                 // longest-first
  const int bh = sb >> 5;
  const int b  = bh >> 4, h = bh & 15;
  const long rowbase = (long)b * S_;

  bf16x8 qf[2];
  {
    const bf16_t* qp = qkv + (rowbase + qt * 64 + w * 16 + l15) * SQKV + h * DK_ + g * 8;
    qf[0] = *reinterpret_cast<const bf16x8*>(qp);
    qf[1] = *reinterpret_cast<const bf16x8*>(qp + 32);
  }
  float mrow[4], ssum[4] = {0.f, 0.f, 0.f, 0.f};
#pragma unroll
  for (int j = 0; j < 4; ++j) mrow[j] = -1e30f;
  f32x4 oacc[4] = {};

  for (int kvt = 0; kvt <= qt; ++kvt) {
    __syncthreads();
    // stage K tile (swizzled) via global_load_lds
#pragma unroll
    for (int i = 0; i < 2; ++i) {
      int L = i * 256 + tid;
      int r = L >> 3, s = L & 7;
      int sc = s ^ (r & 7);
      const bf16_t* gk = qkv + (rowbase + kvt * 64 + r) * SQKV + D_ + h * DK_ + sc * 8;
      gload_lds16(gk, ldsK + (i * 256 + w * 64) * 16);
    }
    // stage V transposed: ldsV[d][kv], pad stride 72.
    // kv = lane (64 consecutive) -> per-store addresses stride 2B across the
    // wave -> 2-way bank aliasing only (free).
    {
      int kv = tid & 63, dq = tid >> 6;
      const bf16_t* gv = qkv + (rowbase + kvt * 64 + kv) * SQKV + 2 * D_ + h * DK_ + dq * 16;
      bf16x8 v0 = *reinterpret_cast<const bf16x8*>(gv);
      bf16x8 v1 = *reinterpret_cast<const bf16x8*>(gv + 8);
      bf16_t* vd = (bf16_t*)ldsV;
#pragma unroll
      for (int e = 0; e < 8; ++e) vd[(dq * 16 + e) * 72 + kv] = v0[e];
#pragma unroll
      for (int e = 0; e < 8; ++e) vd[(dq * 16 + 8 + e) * 72 + kv] = v1[e];
    }
    __syncthreads();

    // S = Q K^T  (4 chunks of 16 kv-cols)
    f32x4 sv[4];
#pragma unroll
    for (int c = 0; c < 4; ++c) {
      f32x4 a = {};
#pragma unroll
      for (int kk = 0; kk < 2; ++kk) {
        int r = c * 16 + l15;
        int s = (kk * 4 + g) ^ (r & 7);
        bf16x8 kf = *reinterpret_cast<const bf16x8*>(ldsK + r * 128 + s * 16);
        a = __builtin_amdgcn_mfma_f32_16x16x32_bf16(qf[kk], kf, a, 0, 0, 0);
      }
      sv[c] = a;
    }
    // scale + causal mask + per-row max
    const bool diag = (kvt == qt);
    float mx[4];
#pragma unroll
    for (int j = 0; j < 4; ++j) {
      int ql = w * 16 + g * 4 + j;
#pragma unroll
      for (int c = 0; c < 4; ++c) {
        float x = sv[c][j] * 0.125f;
        if (diag && (c * 16 + l15) > ql) x = -1e30f;
        sv[c][j] = x;
      }
      mx[j] = fmaxf(fmaxf(sv[0][j], sv[1][j]), fmaxf(sv[2][j], sv[3][j]));
    }
#pragma unroll
    for (int off = 1; off < 16; off <<= 1)
#pragma unroll
      for (int j = 0; j < 4; ++j) mx[j] = fmaxf(mx[j], __shfl_xor(mx[j], off));
    float al[4];
#pragma unroll
    for (int j = 0; j < 4; ++j) {
      float mn = fmaxf(mrow[j], mx[j]);
      al[j] = __expf(mrow[j] - mn);
      mrow[j] = mn;
    }
    // P = exp(S - m) -> per-wave LDS (reshape for PV A-frag), row sums
    float rs[4] = {0.f, 0.f, 0.f, 0.f};
    bf16_t* pw = (bf16_t*)ldsP[w];
#pragma unroll
    for (int c = 0; c < 4; ++c)
#pragma unroll
      for (int j = 0; j < 4; ++j) {
        float p = __expf(sv[c][j] - mrow[j]);
        rs[j] += p;
        pw[(g * 4 + j) * 72 + c * 16 + l15] = (bf16_t)p;
      }
#pragma unroll
    for (int off = 1; off < 16; off <<= 1)
#pragma unroll
      for (int j = 0; j < 4; ++j) rs[j] += __shfl_xor(rs[j], off);
#pragma unroll
    for (int j = 0; j < 4; ++j) ssum[j] = ssum[j] * al[j] + rs[j];
#pragma unroll
    for (int dc = 0; dc < 4; ++dc)
#pragma unroll
      for (int j = 0; j < 4; ++j) oacc[dc][j] *= al[j];
    // O += P V   (A-frag = P from own-wave LDS; B-frag = V from transposed LDS)
#pragma unroll
    for (int ks = 0; ks < 2; ++ks) {
      bf16x8 pf = *reinterpret_cast<const bf16x8*>((bf16_t*)ldsP[w] + l15 * 72 + ks * 32 + g * 8);
#pragma unroll
      for (int dc = 0; dc < 4; ++dc) {
        bf16x8 vf = *reinterpret_cast<const bf16x8*>((bf16_t*)ldsV + (dc * 16 + l15) * 72 + ks * 32 + g * 8);
        oacc[dc] = __builtin_amdgcn_mfma_f32_16x16x32_bf16(pf, vf, oacc[dc], 0, 0, 0);
      }
    }
  }
  // normalize + write O (layout [B*S][D], head h at cols h*64)
#pragma unroll
  for (int j = 0; j < 4; ++j) {
    float inv = 1.0f / ssum[j];
    long r = rowbase + qt * 64 + w * 16 + g * 4 + j;
#pragma unroll
    for (int dc = 0; dc < 4; ++dc)
      Ob[r * D_ + h * DK_ + dc * 16 + l15] = (bf16_t)(oacc[dc][j] * inv);
  }
}

// ---------------- launch ----------------
extern "C" void kernel_launch(void* const* d_in, const int* in_sizes, int n_in,
                              void* d_out, int out_size, void* d_ws, size_t ws_size,
                              hipStream_t stream) {
  const float* x  = (const float*)d_in[0];
  const float* Wq = (const float*)d_in[1];
  const float* Wk = (const float*)d_in[2];
  const float* Wv = (const float*)d_in[3];
  const float* Wo = (const float*)d_in[4];
  float* out = (float*)d_out;

  char* ws = (char*)d_ws;
  bf16_t* xb  = (bf16_t*)(ws);                    // [8192,1024]       16.78 MB
  bf16_t* Wc  = (bf16_t*)(ws + 16777216);         // [3072,1024]        6.29 MB
  bf16_t* Wob = (bf16_t*)(ws + 23068672);         // [1024,1024]        2.10 MB
  bf16_t* QKV = (bf16_t*)(ws + 25165824);         // [8192,3072]       50.33 MB
  bf16_t* Ob  = (bf16_t*)(ws + 75497472);         // [8192,1024]       16.78 MB

  cast_f32_to_bf16<<<8192, 256, 0, stream>>>(x,  xb,            2097152);
  cast_f32_to_bf16<<<1024, 256, 0, stream>>>(Wq, Wc,             262144);
  cast_f32_to_bf16<<<1024, 256, 0, stream>>>(Wk, Wc + 1048576,   262144);
  cast_f32_to_bf16<<<1024, 256, 0, stream>>>(Wv, Wc + 2097152,   262144);
  cast_f32_to_bf16<<<1024, 256, 0, stream>>>(Wo, Wob,            262144);

  // QKV = xb @ Wc^T   [8192,3072]
  gemm_bt<bf16_t><<<dim3(24, 64), 256, 0, stream>>>(xb, Wc, QKV, 8192, 3072, 1024);
  // causal flash attention -> Ob [8192,1024]
  attn_kernel<<<dim3(32, 64), 256, 0, stream>>>(QKV, Ob);
  // out = Ob @ Wo^T  (fp32)
  gemm_bt<float><<<dim3(8, 64), 256, 0, stream>>>(Ob, Wob, out, 8192, 1024, 1024);
}

// Round 5
// 281.584 us; speedup vs baseline: 1.1844x; 1.1844x over previous
//
#include <hip/hip_runtime.h>

typedef __bf16 bf16_t;
using bf16x8 = __attribute__((ext_vector_type(8))) __bf16;
using bf16x4 = __attribute__((ext_vector_type(4))) __bf16;
using f32x4  = __attribute__((ext_vector_type(4))) float;

#define B_   4
#define S_   2048
#define D_   1024
#define H_   16
#define DK_  64
#define SQKV 3072   // QKV buffer row stride (Q|K|V concatenated)

__device__ __forceinline__ void gload_lds16(const void* g, void* l) {
  __builtin_amdgcn_global_load_lds((const __attribute__((address_space(1))) void*)g,
                                   (__attribute__((address_space(3))) void*)l, 16, 0, 0);
}

__device__ __forceinline__ float fast_exp2(float x) {
#if __has_builtin(__builtin_amdgcn_exp2f)
  return __builtin_amdgcn_exp2f(x);
#else
  return __expf(x * 0.69314718f);
#endif
}

// ---------------- fp32 -> bf16 cast (vectorized, optional scale) ----------------
__global__ void cast_f32_to_bf16(const float* __restrict__ in, bf16_t* __restrict__ out,
                                 int n4, float scale) {
  int i = blockIdx.x * 256 + threadIdx.x;
  if (i >= n4) return;
  float4 v = reinterpret_cast<const float4*>(in)[i];
  bf16x4 o;
  o[0] = (bf16_t)(v.x * scale); o[1] = (bf16_t)(v.y * scale);
  o[2] = (bf16_t)(v.z * scale); o[3] = (bf16_t)(v.w * scale);
  reinterpret_cast<bf16x4*>(out)[i] = o;
}

// ---------------- C[M,N] = A[M,K] * B[N,K]^T  (bf16 in, OutT out) ----------------
template <typename OutT>
__global__ void gemm_bt(const bf16_t* __restrict__ A, const bf16_t* __restrict__ Bm,
                        OutT* __restrict__ C, int M, int N, int K) {
  __shared__ alignas(16) char As[16384];
  __shared__ alignas(16) char Bs[16384];
  const int tid  = threadIdx.x;
  const int wid  = tid >> 6, lane = tid & 63;
  const int g    = lane >> 4, l15 = lane & 15;

  int nwg = gridDim.x * gridDim.y;
  int bid = blockIdx.y * gridDim.x + blockIdx.x;
  int sb  = ((nwg & 7) == 0) ? ((bid & 7) * (nwg >> 3) + (bid >> 3)) : bid;
  int bx  = sb % gridDim.x, by = sb / gridDim.x;

  const long row0 = (long)by * 128, col0 = (long)bx * 128;
  const int wr = (wid >> 1) * 64, wc = (wid & 1) * 64;
  f32x4 acc[4][4] = {};

  for (int k0 = 0; k0 < K; k0 += 64) {
    __syncthreads();
#pragma unroll
    for (int i = 0; i < 4; ++i) {
      int L = i * 256 + tid;
      int r = L >> 3, s = L & 7;
      int sc = s ^ (r & 7);
      const bf16_t* ga = A  + (row0 + r) * (long)K + k0 + sc * 8;
      const bf16_t* gb = Bm + (col0 + r) * (long)K + k0 + sc * 8;
      gload_lds16(ga, As + (i * 256 + wid * 64) * 16);
      gload_lds16(gb, Bs + (i * 256 + wid * 64) * 16);
    }
    __syncthreads();
#pragma unroll
    for (int kk = 0; kk < 2; ++kk) {
      bf16x8 af[4], bfr[4];
#pragma unroll
      for (int m = 0; m < 4; ++m) {
        int r = wr + m * 16 + l15;
        int s = (kk * 4 + g) ^ (r & 7);
        af[m] = *reinterpret_cast<const bf16x8*>(As + r * 128 + s * 16);
      }
#pragma unroll
      for (int n = 0; n < 4; ++n) {
        int r = wc + n * 16 + l15;
        int s = (kk * 4 + g) ^ (r & 7);
        bfr[n] = *reinterpret_cast<const bf16x8*>(Bs + r * 128 + s * 16);
      }
#pragma unroll
      for (int m = 0; m < 4; ++m)
#pragma unroll
        for (int n = 0; n < 4; ++n)
          acc[m][n] = __builtin_amdgcn_mfma_f32_16x16x32_bf16(af[m], bfr[n], acc[m][n], 0, 0, 0);
    }
  }
#pragma unroll
  for (int m = 0; m < 4; ++m)
#pragma unroll
    for (int n = 0; n < 4; ++n)
#pragma unroll
      for (int j = 0; j < 4; ++j) {
        long r = row0 + wr + m * 16 + g * 4 + j;
        long c = col0 + wc + n * 16 + l15;
        C[r * (long)N + c] = (OutT)acc[m][n][j];
      }
}

// ---------------- V transpose: QKV V-part -> VT[(b*16+h)*64+d][s] ----------------
__global__ void vtrans_kernel(const bf16_t* __restrict__ qkv, bf16_t* __restrict__ VT) {
  __shared__ bf16_t t[64 * 65];
  const int tid = threadIdx.x;
  const int s0 = blockIdx.x * 64;
  const int bh = blockIdx.y, b = bh >> 4, h = bh & 15;
  {
    int sl = tid >> 2, dc = tid & 3;
    const bf16_t* src = qkv + ((long)(b * S_ + s0 + sl)) * SQKV + 2 * D_ + h * DK_ + dc * 16;
    bf16x8 v0 = *reinterpret_cast<const bf16x8*>(src);
    bf16x8 v1 = *reinterpret_cast<const bf16x8*>(src + 8);
#pragma unroll
    for (int e = 0; e < 8; ++e) t[sl * 65 + dc * 16 + e] = v0[e];
#pragma unroll
    for (int e = 0; e < 8; ++e) t[sl * 65 + dc * 16 + 8 + e] = v1[e];
  }
  __syncthreads();
  {
    int d = tid >> 2, sc = tid & 3;
    bf16x8 o0, o1;
#pragma unroll
    for (int e = 0; e < 8; ++e) o0[e] = t[(sc * 16 + e) * 65 + d];
#pragma unroll
    for (int e = 0; e < 8; ++e) o1[e] = t[(sc * 16 + 8 + e) * 65 + d];
    bf16_t* dst = VT + ((long)(bh * 64 + d)) * S_ + s0 + sc * 16;
    *reinterpret_cast<bf16x8*>(dst) = o0;
    *reinterpret_cast<bf16x8*>(dst + 8) = o1;
  }
}

// ---------------- flash attention (causal), bf16 MFMA ----------------
// grid: 2048 blocks (32 qt x 64 bh), 4 waves x 16 q-rows, KVBLK=64.
// K/V double-buffered gload_lds (stage-early, 1 barrier/iter), XOR-swizzled LDS,
// log2-domain softmax w/ defer-max (THR=8), per-lane deferred row sums.
__global__ __launch_bounds__(256, 4)
void attn_kernel(const bf16_t* __restrict__ qkv, const bf16_t* __restrict__ VT,
                 bf16_t* __restrict__ Ob) {
  __shared__ alignas(16) char ldsK[2][8192];   // [64 kv][64 d], swizzled
  __shared__ alignas(16) char ldsV[2][8192];   // [64 d][64 kv], swizzled
  __shared__ alignas(16) char ldsP[4][2048];   // per-wave [16 q][64 kv], chunk-XOR swz
  const int tid = threadIdx.x;
  const int w   = tid >> 6, lane = tid & 63;
  const int g   = lane >> 4, l15 = lane & 15;

  int bid = blockIdx.y * 32 + blockIdx.x;
  int sb  = (bid & 7) * 256 + (bid >> 3);      // XCD-bijective
  const int qt = 31 - (sb & 31);               // longest-first
  const int bh = sb >> 5;
  const int b  = bh >> 4, h = bh & 15;
  const long rowbase = (long)b * S_;

  bf16x8 qf[2];
  {
    const bf16_t* qp = qkv + (rowbase + qt * 64 + w * 16 + l15) * SQKV + h * DK_ + g * 8;
    qf[0] = *reinterpret_cast<const bf16x8*>(qp);
    qf[1] = *reinterpret_cast<const bf16x8*>(qp + 32);
  }
  float m_j[4], ssum[4] = {0.f, 0.f, 0.f, 0.f};
#pragma unroll
  for (int j = 0; j < 4; ++j) m_j[j] = -1e30f;
  f32x4 oacc[4] = {};

  const bf16_t* kbase = qkv + rowbase * SQKV + D_ + h * DK_;
  const bf16_t* vbase = VT + (long)bh * 64 * S_;

  auto stageK = [&](int kvt, int buf) {
#pragma unroll
    for (int i = 0; i < 2; ++i) {
      int L = i * 256 + tid;
      int r = L >> 3, s = L & 7;
      int sc = s ^ (r & 7);
      gload_lds16(kbase + (long)(kvt * 64 + r) * SQKV + sc * 8,
                  ldsK[buf] + L * 16);
    }
  };
  auto stageV = [&](int kvt, int buf) {
#pragma unroll
    for (int i = 0; i < 2; ++i) {
      int L = i * 256 + tid;
      int r = L >> 3, s = L & 7;    // r = d row
      int sc = s ^ (r & 7);
      gload_lds16(vbase + (long)r * S_ + kvt * 64 + sc * 8,
                  ldsV[buf] + L * 16);
    }
  };

  stageK(0, 0); stageV(0, 0);
  __syncthreads();

  for (int kvt = 0; kvt <= qt; ++kvt) {
    const int cur = kvt & 1;
    if (kvt < qt) { stageK(kvt + 1, cur ^ 1); stageV(kvt + 1, cur ^ 1); }

    // ---- S = Q K^T (scale + log2e folded into Wq) ----
    f32x4 sv[4];
    __builtin_amdgcn_s_setprio(1);
#pragma unroll
    for (int c = 0; c < 4; ++c) {
      f32x4 a = {};
#pragma unroll
      for (int kk = 0; kk < 2; ++kk) {
        int r = c * 16 + l15;
        int s = (kk * 4 + g) ^ (l15 & 7);
        bf16x8 kf = *reinterpret_cast<const bf16x8*>(ldsK[cur] + r * 128 + s * 16);
        a = __builtin_amdgcn_mfma_f32_16x16x32_bf16(qf[kk], kf, a, 0, 0, 0);
      }
      sv[c] = a;
    }
    __builtin_amdgcn_s_setprio(0);

    if (kvt == qt) {            // causal mask, diagonal tile only (uniform branch)
#pragma unroll
      for (int j = 0; j < 4; ++j) {
        int ql = w * 16 + g * 4 + j;
#pragma unroll
        for (int c = 0; c < 4; ++c)
          if ((c * 16 + l15) > ql) sv[c][j] = -1e30f;
      }
    }

    // ---- defer-max online softmax (log2 domain) ----
    float mx[4];
#pragma unroll
    for (int j = 0; j < 4; ++j)
      mx[j] = fmaxf(fmaxf(sv[0][j], sv[1][j]), fmaxf(sv[2][j], sv[3][j]));
    bool need = false;
#pragma unroll
    for (int j = 0; j < 4; ++j) need |= (mx[j] > m_j[j] + 8.0f);
    if (__any(need)) {
#pragma unroll
      for (int off = 1; off < 16; off <<= 1)
#pragma unroll
        for (int j = 0; j < 4; ++j) mx[j] = fmaxf(mx[j], __shfl_xor(mx[j], off));
#pragma unroll
      for (int j = 0; j < 4; ++j) {
        float mn = fmaxf(m_j[j], mx[j]);
        float al = fast_exp2(m_j[j] - mn);
        m_j[j] = mn;
        ssum[j] *= al;
#pragma unroll
        for (int dc = 0; dc < 4; ++dc) oacc[dc][j] *= al;
      }
    }

    // ---- P = exp2(S - m) -> per-wave LDS (chunk-XOR swizzled), partial sums ----
    bf16_t* pw = (bf16_t*)ldsP[w];
#pragma unroll
    for (int c = 0; c < 4; ++c)
#pragma unroll
      for (int j = 0; j < 4; ++j) {
        float p = fast_exp2(sv[c][j] - m_j[j]);
        ssum[j] += p;
        int q = g * 4 + j;
        int chunk = (c * 2 + (l15 >> 3)) ^ (q & 7);
        pw[q * 64 + chunk * 8 + (l15 & 7)] = (bf16_t)p;
      }

    // ---- O += P V ----
    __builtin_amdgcn_s_setprio(1);
#pragma unroll
    for (int ks = 0; ks < 2; ++ks) {
      int sp = (ks * 4 + g) ^ (l15 & 7);
      bf16x8 pf = *reinterpret_cast<const bf16x8*>(ldsP[w] + l15 * 128 + sp * 16);
#pragma unroll
      for (int dc = 0; dc < 4; ++dc) {
        int r = dc * 16 + l15;
        int s = (ks * 4 + g) ^ (l15 & 7);
        bf16x8 vf = *reinterpret_cast<const bf16x8*>(ldsV[cur] + r * 128 + s * 16);
        oacc[dc] = __builtin_amdgcn_mfma_f32_16x16x32_bf16(pf, vf, oacc[dc], 0, 0, 0);
      }
    }
    __builtin_amdgcn_s_setprio(0);
    __syncthreads();
  }

  // final row-sum reduce (deferred) + normalize + write
#pragma unroll
  for (int off = 1; off < 16; off <<= 1)
#pragma unroll
    for (int j = 0; j < 4; ++j) ssum[j] += __shfl_xor(ssum[j], off);
#pragma unroll
  for (int j = 0; j < 4; ++j) {
    float inv = 1.0f / ssum[j];
    long r = rowbase + qt * 64 + w * 16 + g * 4 + j;
#pragma unroll
    for (int dc = 0; dc < 4; ++dc)
      Ob[r * D_ + h * DK_ + dc * 16 + l15] = (bf16_t)(oacc[dc][j] * inv);
  }
}

// ---------------- launch ----------------
extern "C" void kernel_launch(void* const* d_in, const int* in_sizes, int n_in,
                              void* d_out, int out_size, void* d_ws, size_t ws_size,
                              hipStream_t stream) {
  const float* x  = (const float*)d_in[0];
  const float* Wq = (const float*)d_in[1];
  const float* Wk = (const float*)d_in[2];
  const float* Wv = (const float*)d_in[3];
  const float* Wo = (const float*)d_in[4];
  float* out = (float*)d_out;

  char* ws = (char*)d_ws;
  bf16_t* xb  = (bf16_t*)(ws);                    // [8192,1024]  (reused as VT later)
  bf16_t* Wc  = (bf16_t*)(ws + 16777216);         // [3072,1024]
  bf16_t* Wob = (bf16_t*)(ws + 23068672);         // [1024,1024]
  bf16_t* QKV = (bf16_t*)(ws + 25165824);         // [8192,3072]
  bf16_t* Ob  = (bf16_t*)(ws + 75497472);         // [8192,1024]
  bf16_t* VT  = xb;                               // [4096,2048] overlays dead xb

  const float QSCALE = 0.18033688f;               // 0.125 * log2(e)

  cast_f32_to_bf16<<<8192, 256, 0, stream>>>(x,  xb,            2097152, 1.0f);
  cast_f32_to_bf16<<<1024, 256, 0, stream>>>(Wq, Wc,             262144, QSCALE);
  cast_f32_to_bf16<<<1024, 256, 0, stream>>>(Wk, Wc + 1048576,   262144, 1.0f);
  cast_f32_to_bf16<<<1024, 256, 0, stream>>>(Wv, Wc + 2097152,   262144, 1.0f);
  cast_f32_to_bf16<<<1024, 256, 0, stream>>>(Wo, Wob,            262144, 1.0f);

  gemm_bt<bf16_t><<<dim3(24, 64), 256, 0, stream>>>(xb, Wc, QKV, 8192, 3072, 1024);
  vtrans_kernel<<<dim3(32, 64), 256, 0, stream>>>(QKV, VT);       // xb dead now
  attn_kernel<<<dim3(32, 64), 256, 0, stream>>>(QKV, VT, Ob);
  gemm_bt<float><<<dim3(8, 64), 256, 0, stream>>>(Ob, Wob, out, 8192, 1024, 1024);
}

// Round 7
// 281.252 us; speedup vs baseline: 1.1858x; 1.0012x over previous
//
#include <hip/hip_runtime.h>

typedef __bf16 bf16_t;
using bf16x8 = __attribute__((ext_vector_type(8))) __bf16;
using bf16x4 = __attribute__((ext_vector_type(4))) __bf16;
using f32x4  = __attribute__((ext_vector_type(4))) float;

#define B_   4
#define S_   2048
#define D_   1024
#define H_   16
#define DK_  64
#define SQKV 3072   // QKV buffer row stride (Q|K|V concatenated)

__device__ __forceinline__ void gload_lds16(const void* g, void* l) {
  __builtin_amdgcn_global_load_lds((const __attribute__((address_space(1))) void*)g,
                                   (__attribute__((address_space(3))) void*)l, 16, 0, 0);
}

__device__ __forceinline__ float fast_exp2(float x) {
#if __has_builtin(__builtin_amdgcn_exp2f)
  return __builtin_amdgcn_exp2f(x);
#else
  return __expf(x * 0.69314718f);
#endif
}

// ---------------- fp32 -> bf16 cast (vectorized, optional scale) ----------------
__global__ void cast_f32_to_bf16(const float* __restrict__ in, bf16_t* __restrict__ out,
                                 int n4, float scale) {
  int i = blockIdx.x * 256 + threadIdx.x;
  if (i >= n4) return;
  float4 v = reinterpret_cast<const float4*>(in)[i];
  bf16x4 o;
  o[0] = (bf16_t)(v.x * scale); o[1] = (bf16_t)(v.y * scale);
  o[2] = (bf16_t)(v.z * scale); o[3] = (bf16_t)(v.w * scale);
  reinterpret_cast<bf16x4*>(out)[i] = o;
}

// ---------------- C[M,N] = A[M,K] * B[N,K]^T  (bf16 in, OutT out) ----------------
template <typename OutT>
__global__ void gemm_bt(const bf16_t* __restrict__ A, const bf16_t* __restrict__ Bm,
                        OutT* __restrict__ C, int M, int N, int K) {
  __shared__ alignas(16) char As[16384];
  __shared__ alignas(16) char Bs[16384];
  const int tid  = threadIdx.x;
  const int wid  = tid >> 6, lane = tid & 63;
  const int g    = lane >> 4, l15 = lane & 15;

  int nwg = gridDim.x * gridDim.y;
  int bid = blockIdx.y * gridDim.x + blockIdx.x;
  int sb  = ((nwg & 7) == 0) ? ((bid & 7) * (nwg >> 3) + (bid >> 3)) : bid;
  int bx  = sb % gridDim.x, by = sb / gridDim.x;

  const long row0 = (long)by * 128, col0 = (long)bx * 128;
  const int wr = (wid >> 1) * 64, wc = (wid & 1) * 64;
  f32x4 acc[4][4] = {};

  for (int k0 = 0; k0 < K; k0 += 64) {
    __syncthreads();
#pragma unroll
    for (int i = 0; i < 4; ++i) {
      int L = i * 256 + tid;
      int r = L >> 3, s = L & 7;
      int sc = s ^ (r & 7);
      const bf16_t* ga = A  + (row0 + r) * (long)K + k0 + sc * 8;
      const bf16_t* gb = Bm + (col0 + r) * (long)K + k0 + sc * 8;
      gload_lds16(ga, As + (i * 256 + wid * 64) * 16);
      gload_lds16(gb, Bs + (i * 256 + wid * 64) * 16);
    }
    __syncthreads();
#pragma unroll
    for (int kk = 0; kk < 2; ++kk) {
      bf16x8 af[4], bfr[4];
#pragma unroll
      for (int m = 0; m < 4; ++m) {
        int r = wr + m * 16 + l15;
        int s = (kk * 4 + g) ^ (r & 7);
        af[m] = *reinterpret_cast<const bf16x8*>(As + r * 128 + s * 16);
      }
#pragma unroll
      for (int n = 0; n < 4; ++n) {
        int r = wc + n * 16 + l15;
        int s = (kk * 4 + g) ^ (r & 7);
        bfr[n] = *reinterpret_cast<const bf16x8*>(Bs + r * 128 + s * 16);
      }
#pragma unroll
      for (int m = 0; m < 4; ++m)
#pragma unroll
        for (int n = 0; n < 4; ++n)
          acc[m][n] = __builtin_amdgcn_mfma_f32_16x16x32_bf16(af[m], bfr[n], acc[m][n], 0, 0, 0);
    }
  }
#pragma unroll
  for (int m = 0; m < 4; ++m)
#pragma unroll
    for (int n = 0; n < 4; ++n)
#pragma unroll
      for (int j = 0; j < 4; ++j) {
        long r = row0 + wr + m * 16 + g * 4 + j;
        long c = col0 + wc + n * 16 + l15;
        C[r * (long)N + c] = (OutT)acc[m][n][j];
      }
}

// ---------------- V transpose: QKV V-part -> VT[(b*16+h)*64+d][s] ----------------
__global__ void vtrans_kernel(const bf16_t* __restrict__ qkv, bf16_t* __restrict__ VT) {
  __shared__ bf16_t t[64 * 65];
  const int tid = threadIdx.x;
  const int s0 = blockIdx.x * 64;
  const int bh = blockIdx.y, b = bh >> 4, h = bh & 15;
  {
    int sl = tid >> 2, dc = tid & 3;
    const bf16_t* src = qkv + ((long)(b * S_ + s0 + sl)) * SQKV + 2 * D_ + h * DK_ + dc * 16;
    bf16x8 v0 = *reinterpret_cast<const bf16x8*>(src);
    bf16x8 v1 = *reinterpret_cast<const bf16x8*>(src + 8);
#pragma unroll
    for (int e = 0; e < 8; ++e) t[sl * 65 + dc * 16 + e] = v0[e];
#pragma unroll
    for (int e = 0; e < 8; ++e) t[sl * 65 + dc * 16 + 8 + e] = v1[e];
  }
  __syncthreads();
  {
    int d = tid >> 2, sc = tid & 3;
    bf16x8 o0, o1;
#pragma unroll
    for (int e = 0; e < 8; ++e) o0[e] = t[(sc * 16 + e) * 65 + d];
#pragma unroll
    for (int e = 0; e < 8; ++e) o1[e] = t[(sc * 16 + 8 + e) * 65 + d];
    bf16_t* dst = VT + ((long)(bh * 64 + d)) * S_ + s0 + sc * 16;
    *reinterpret_cast<bf16x8*>(dst) = o0;
    *reinterpret_cast<bf16x8*>(dst + 8) = o1;
  }
}

// ---------------- flash attention (causal), bf16 MFMA ----------------
// grid: 2048 blocks (32 qt x 64 bh), 4 waves x 16 q-rows, KVBLK=64.
// Pipeline (race-free, 1 barrier/iter):
//   vmcnt(0) [own tile-t loads, issued a full compute-phase ago]
//   s_barrier [certifies ALL waves' tile-t landed + buf[cur^1] reads done]
//   stage(t+1) [stays in flight across compute]
//   compute(t)
__global__ __launch_bounds__(256, 4)
void attn_kernel(const bf16_t* __restrict__ qkv, const bf16_t* __restrict__ VT,
                 bf16_t* __restrict__ Ob) {
  __shared__ alignas(16) char ldsK[2][8192];   // [64 kv][64 d], swizzled
  __shared__ alignas(16) char ldsV[2][8192];   // [64 d][64 kv], swizzled
  __shared__ alignas(16) char ldsP[4][2048];   // per-wave [16 q][64 kv], chunk-XOR swz
  const int tid = threadIdx.x;
  const int w   = tid >> 6, lane = tid & 63;
  const int g   = lane >> 4, l15 = lane & 15;

  int bid = blockIdx.y * 32 + blockIdx.x;
  int sb  = (bid & 7) * 256 + (bid >> 3);      // XCD-bijective
  const int qt = 31 - (sb & 31);               // longest-first
  const int bh = sb >> 5;
  const int b  = bh >> 4, h = bh & 15;
  const long rowbase = (long)b * S_;

  bf16x8 qf[2];
  {
    const bf16_t* qp = qkv + (rowbase + qt * 64 + w * 16 + l15) * SQKV + h * DK_ + g * 8;
    qf[0] = *reinterpret_cast<const bf16x8*>(qp);
    qf[1] = *reinterpret_cast<const bf16x8*>(qp + 32);
  }
  float m_j[4], ssum[4] = {0.f, 0.f, 0.f, 0.f};
#pragma unroll
  for (int j = 0; j < 4; ++j) m_j[j] = -1e30f;
  f32x4 oacc[4] = {};

  const bf16_t* kbase = qkv + rowbase * SQKV + D_ + h * DK_;
  const bf16_t* vbase = VT + (long)bh * 64 * S_;

  auto stageK = [&](int kvt, int buf) {
#pragma unroll
    for (int i = 0; i < 2; ++i) {
      int L = i * 256 + tid;
      int r = L >> 3, s = L & 7;
      int sc = s ^ (r & 7);
      gload_lds16(kbase + (long)(kvt * 64 + r) * SQKV + sc * 8,
                  ldsK[buf] + L * 16);
    }
  };
  auto stageV = [&](int kvt, int buf) {
#pragma unroll
    for (int i = 0; i < 2; ++i) {
      int L = i * 256 + tid;
      int r = L >> 3, s = L & 7;    // r = d row
      int sc = s ^ (r & 7);
      gload_lds16(vbase + (long)r * S_ + kvt * 64 + sc * 8,
                  ldsV[buf] + L * 16);
    }
  };

  stageK(0, 0); stageV(0, 0);                  // 4 VMEM ops in flight

  for (int kvt = 0; kvt <= qt; ++kvt) {
    const int cur = kvt & 1;
    // (1) own tile-kvt loads landed (issued before compute(kvt-1) -> latency hidden)
    asm volatile("s_waitcnt vmcnt(0)" ::: "memory");
    // (2) rendezvous AFTER the wait: all waves' tile-kvt data now in LDS, and all
    //     waves finished reading buf[cur^1] during compute(kvt-1) -> safe to overwrite.
    __builtin_amdgcn_s_barrier();
    // (3) prefetch tile kvt+1; stays in flight across compute(kvt).
    if (kvt < qt) { stageK(kvt + 1, cur ^ 1); stageV(kvt + 1, cur ^ 1); }

    // ---- S = Q K^T (scale + log2e folded into Wq) ----
    f32x4 sv[4];
    __builtin_amdgcn_s_setprio(1);
#pragma unroll
    for (int c = 0; c < 4; ++c) {
      f32x4 a = {};
#pragma unroll
      for (int kk = 0; kk < 2; ++kk) {
        int r = c * 16 + l15;
        int s = (kk * 4 + g) ^ (l15 & 7);
        bf16x8 kf = *reinterpret_cast<const bf16x8*>(ldsK[cur] + r * 128 + s * 16);
        a = __builtin_amdgcn_mfma_f32_16x16x32_bf16(qf[kk], kf, a, 0, 0, 0);
      }
      sv[c] = a;
    }
    __builtin_amdgcn_s_setprio(0);

    if (kvt == qt) {            // causal mask, diagonal tile only (uniform branch)
#pragma unroll
      for (int j = 0; j < 4; ++j) {
        int ql = w * 16 + g * 4 + j;
#pragma unroll
        for (int c = 0; c < 4; ++c)
          if ((c * 16 + l15) > ql) sv[c][j] = -1e30f;
      }
    }

    // ---- defer-max online softmax (log2 domain) ----
    float mx[4];
#pragma unroll
    for (int j = 0; j < 4; ++j)
      mx[j] = fmaxf(fmaxf(sv[0][j], sv[1][j]), fmaxf(sv[2][j], sv[3][j]));
    bool need = false;
#pragma unroll
    for (int j = 0; j < 4; ++j) need |= (mx[j] > m_j[j] + 8.0f);
    if (__any(need)) {
#pragma unroll
      for (int off = 1; off < 16; off <<= 1)
#pragma unroll
        for (int j = 0; j < 4; ++j) mx[j] = fmaxf(mx[j], __shfl_xor(mx[j], off));
#pragma unroll
      for (int j = 0; j < 4; ++j) {
        float mn = fmaxf(m_j[j], mx[j]);
        float al = fast_exp2(m_j[j] - mn);
        m_j[j] = mn;
        ssum[j] *= al;
#pragma unroll
        for (int dc = 0; dc < 4; ++dc) oacc[dc][j] *= al;
      }
    }

    // ---- P = exp2(S - m) -> per-wave LDS (chunk-XOR swizzled), partial sums ----
    bf16_t* pw = (bf16_t*)ldsP[w];
#pragma unroll
    for (int c = 0; c < 4; ++c)
#pragma unroll
      for (int j = 0; j < 4; ++j) {
        float p = fast_exp2(sv[c][j] - m_j[j]);
        ssum[j] += p;
        int q = g * 4 + j;
        int chunk = (c * 2 + (l15 >> 3)) ^ (q & 7);
        pw[q * 64 + chunk * 8 + (l15 & 7)] = (bf16_t)p;
      }

    // ---- O += P V ----
    __builtin_amdgcn_s_setprio(1);
#pragma unroll
    for (int ks = 0; ks < 2; ++ks) {
      int sp = (ks * 4 + g) ^ (l15 & 7);
      bf16x8 pf = *reinterpret_cast<const bf16x8*>(ldsP[w] + l15 * 128 + sp * 16);
#pragma unroll
      for (int dc = 0; dc < 4; ++dc) {
        int r = dc * 16 + l15;
        int s = (ks * 4 + g) ^ (l15 & 7);
        bf16x8 vf = *reinterpret_cast<const bf16x8*>(ldsV[cur] + r * 128 + s * 16);
        oacc[dc] = __builtin_amdgcn_mfma_f32_16x16x32_bf16(pf, vf, oacc[dc], 0, 0, 0);
      }
    }
    __builtin_amdgcn_s_setprio(0);
  }

  // final row-sum reduce (deferred) + normalize + write
#pragma unroll
  for (int off = 1; off < 16; off <<= 1)
#pragma unroll
    for (int j = 0; j < 4; ++j) ssum[j] += __shfl_xor(ssum[j], off);
#pragma unroll
  for (int j = 0; j < 4; ++j) {
    float inv = 1.0f / ssum[j];
    long r = rowbase + qt * 64 + w * 16 + g * 4 + j;
#pragma unroll
    for (int dc = 0; dc < 4; ++dc)
      Ob[r * D_ + h * DK_ + dc * 16 + l15] = (bf16_t)(oacc[dc][j] * inv);
  }
}

// ---------------- launch ----------------
extern "C" void kernel_launch(void* const* d_in, const int* in_sizes, int n_in,
                              void* d_out, int out_size, void* d_ws, size_t ws_size,
                              hipStream_t stream) {
  const float* x  = (const float*)d_in[0];
  const float* Wq = (const float*)d_in[1];
  const float* Wk = (const float*)d_in[2];
  const float* Wv = (const float*)d_in[3];
  const float* Wo = (const float*)d_in[4];
  float* out = (float*)d_out;

  char* ws = (char*)d_ws;
  bf16_t* xb  = (bf16_t*)(ws);                    // [8192,1024]  (reused as VT later)
  bf16_t* Wc  = (bf16_t*)(ws + 16777216);         // [3072,1024]
  bf16_t* Wob = (bf16_t*)(ws + 23068672);         // [1024,1024]
  bf16_t* QKV = (bf16_t*)(ws + 25165824);         // [8192,3072]
  bf16_t* Ob  = (bf16_t*)(ws + 75497472);         // [8192,1024]
  bf16_t* VT  = xb;                               // [4096,2048] overlays dead xb

  const float QSCALE = 0.18033688f;               // 0.125 * log2(e)

  cast_f32_to_bf16<<<8192, 256, 0, stream>>>(x,  xb,            2097152, 1.0f);
  cast_f32_to_bf16<<<1024, 256, 0, stream>>>(Wq, Wc,             262144, QSCALE);
  cast_f32_to_bf16<<<1024, 256, 0, stream>>>(Wk, Wc + 1048576,   262144, 1.0f);
  cast_f32_to_bf16<<<1024, 256, 0, stream>>>(Wv, Wc + 2097152,   262144, 1.0f);
  cast_f32_to_bf16<<<1024, 256, 0, stream>>>(Wo, Wob,            262144, 1.0f);

  gemm_bt<bf16_t><<<dim3(24, 64), 256, 0, stream>>>(xb, Wc, QKV, 8192, 3072, 1024);
  vtrans_kernel<<<dim3(32, 64), 256, 0, stream>>>(QKV, VT);       // xb dead now
  attn_kernel<<<dim3(32, 64), 256, 0, stream>>>(QKV, VT, Ob);
  gemm_bt<float><<<dim3(8, 64), 256, 0, stream>>>(Ob, Wob, out, 8192, 1024, 1024);
}

// Round 8
// 254.764 us; speedup vs baseline: 1.3091x; 1.1040x over previous
//
#include <hip/hip_runtime.h>

typedef __bf16 bf16_t;
using bf16x8 = __attribute__((ext_vector_type(8))) __bf16;
using bf16x4 = __attribute__((ext_vector_type(4))) __bf16;
using f32x4  = __attribute__((ext_vector_type(4))) float;

#define B_   4
#define S_   2048
#define D_   1024
#define H_   16
#define DK_  64
#define SQKV 3072   // QKV buffer row stride (Q|K|V concatenated)

__device__ __forceinline__ void gload_lds16(const void* g, void* l) {
  __builtin_amdgcn_global_load_lds((const __attribute__((address_space(1))) void*)g,
                                   (__attribute__((address_space(3))) void*)l, 16, 0, 0);
}

__device__ __forceinline__ float fast_exp2(float x) {
#if __has_builtin(__builtin_amdgcn_exp2f)
  return __builtin_amdgcn_exp2f(x);
#else
  return __expf(x * 0.69314718f);
#endif
}

// ---------------- fp32 -> bf16 cast (vectorized, optional scale) ----------------
__global__ void cast_f32_to_bf16(const float* __restrict__ in, bf16_t* __restrict__ out,
                                 int n4, float scale) {
  int i = blockIdx.x * 256 + threadIdx.x;
  if (i >= n4) return;
  float4 v = reinterpret_cast<const float4*>(in)[i];
  bf16x4 o;
  o[0] = (bf16_t)(v.x * scale); o[1] = (bf16_t)(v.y * scale);
  o[2] = (bf16_t)(v.z * scale); o[3] = (bf16_t)(v.w * scale);
  reinterpret_cast<bf16x4*>(out)[i] = o;
}

// ---------------- C[M,N] = A[M,K] * B[N,K]^T  (bf16 in, OutT out) ----------------
template <typename OutT>
__global__ void gemm_bt(const bf16_t* __restrict__ A, const bf16_t* __restrict__ Bm,
                        OutT* __restrict__ C, int M, int N, int K) {
  __shared__ alignas(16) char As[16384];
  __shared__ alignas(16) char Bs[16384];
  const int tid  = threadIdx.x;
  const int wid  = tid >> 6, lane = tid & 63;
  const int g    = lane >> 4, l15 = lane & 15;

  int nwg = gridDim.x * gridDim.y;
  int bid = blockIdx.y * gridDim.x + blockIdx.x;
  int sb  = ((nwg & 7) == 0) ? ((bid & 7) * (nwg >> 3) + (bid >> 3)) : bid;
  int bx  = sb % gridDim.x, by = sb / gridDim.x;

  const long row0 = (long)by * 128, col0 = (long)bx * 128;
  const int wr = (wid >> 1) * 64, wc = (wid & 1) * 64;
  f32x4 acc[4][4] = {};

  for (int k0 = 0; k0 < K; k0 += 64) {
    __syncthreads();
#pragma unroll
    for (int i = 0; i < 4; ++i) {
      int L = i * 256 + tid;
      int r = L >> 3, s = L & 7;
      int sc = s ^ (r & 7);
      const bf16_t* ga = A  + (row0 + r) * (long)K + k0 + sc * 8;
      const bf16_t* gb = Bm + (col0 + r) * (long)K + k0 + sc * 8;
      gload_lds16(ga, As + (i * 256 + wid * 64) * 16);
      gload_lds16(gb, Bs + (i * 256 + wid * 64) * 16);
    }
    __syncthreads();
#pragma unroll
    for (int kk = 0; kk < 2; ++kk) {
      bf16x8 af[4], bfr[4];
#pragma unroll
      for (int m = 0; m < 4; ++m) {
        int r = wr + m * 16 + l15;
        int s = (kk * 4 + g) ^ (r & 7);
        af[m] = *reinterpret_cast<const bf16x8*>(As + r * 128 + s * 16);
      }
#pragma unroll
      for (int n = 0; n < 4; ++n) {
        int r = wc + n * 16 + l15;
        int s = (kk * 4 + g) ^ (r & 7);
        bfr[n] = *reinterpret_cast<const bf16x8*>(Bs + r * 128 + s * 16);
      }
#pragma unroll
      for (int m = 0; m < 4; ++m)
#pragma unroll
        for (int n = 0; n < 4; ++n)
          acc[m][n] = __builtin_amdgcn_mfma_f32_16x16x32_bf16(af[m], bfr[n], acc[m][n], 0, 0, 0);
    }
  }
#pragma unroll
  for (int m = 0; m < 4; ++m)
#pragma unroll
    for (int n = 0; n < 4; ++n)
#pragma unroll
      for (int j = 0; j < 4; ++j) {
        long r = row0 + wr + m * 16 + g * 4 + j;
        long c = col0 + wc + n * 16 + l15;
        C[r * (long)N + c] = (OutT)acc[m][n][j];
      }
}

// ---------------- V transpose+permute: QKV V-part -> VT[(b*16+h)*64+d][pos] ------
// Column order within each 64-kv tile is the PV k-axis permutation:
//   pos = (kv>>5)*32 + ((kv>>2)&3)*8 + ((kv>>4)&1)*4 + (kv&3)
// (inverse: kv(p) = (p>>5)*32 + ((p>>2)&1)*16 + ((p>>3)&3)*4 + (p&3))
// so that each lane's PV B-fragment (P^T) is its own registers (no cross-lane).
__global__ void vtrans_kernel(const bf16_t* __restrict__ qkv, bf16_t* __restrict__ VT) {
  __shared__ bf16_t t[64 * 65];
  const int tid = threadIdx.x;
  const int s0 = blockIdx.x * 64;
  const int bh = blockIdx.y, b = bh >> 4, h = bh & 15;
  {
    int sl = tid >> 2, dc = tid & 3;
    const bf16_t* src = qkv + ((long)(b * S_ + s0 + sl)) * SQKV + 2 * D_ + h * DK_ + dc * 16;
    bf16x8 v0 = *reinterpret_cast<const bf16x8*>(src);
    bf16x8 v1 = *reinterpret_cast<const bf16x8*>(src + 8);
#pragma unroll
    for (int e = 0; e < 8; ++e) t[sl * 65 + dc * 16 + e] = v0[e];
#pragma unroll
    for (int e = 0; e < 8; ++e) t[sl * 65 + dc * 16 + 8 + e] = v1[e];
  }
  __syncthreads();
  {
    int d = tid >> 2, sc = tid & 3;
    bf16x8 o0, o1;
#pragma unroll
    for (int e = 0; e < 8; ++e) {
      int p  = sc * 16 + e;
      int kv = ((p >> 5) << 5) + (((p >> 2) & 1) << 4) + (((p >> 3) & 3) << 2) + (p & 3);
      o0[e] = t[kv * 65 + d];
    }
#pragma unroll
    for (int e = 0; e < 8; ++e) {
      int p  = sc * 16 + 8 + e;
      int kv = ((p >> 5) << 5) + (((p >> 2) & 1) << 4) + (((p >> 3) & 3) << 2) + (p & 3);
      o1[e] = t[kv * 65 + d];
    }
    bf16_t* dst = VT + ((long)(bh * 64 + d)) * S_ + s0 + sc * 16;
    *reinterpret_cast<bf16x8*>(dst) = o0;
    *reinterpret_cast<bf16x8*>(dst + 8) = o1;
  }
}

// ---------------- flash attention (causal), bf16 MFMA, swapped operands ---------
// S^T = mfma(K, Q): q = l15 (lane-local softmax rows), kv = (c,g,j).
// O^T = mfma(V^T, P^T): each lane's P^T B-frag = its own exp'd registers
// (k-axis permutation pre-applied to VT by vtrans_kernel). P never touches LDS.
__global__ __launch_bounds__(256, 5)
void attn_kernel(const bf16_t* __restrict__ qkv, const bf16_t* __restrict__ VT,
                 bf16_t* __restrict__ Ob) {
  __shared__ alignas(16) char ldsK[2][8192];   // [64 kv][64 d], swizzled
  __shared__ alignas(16) char ldsV[2][8192];   // [64 d][64 pos], swizzled
  const int tid = threadIdx.x;
  const int w   = tid >> 6, lane = tid & 63;
  const int g   = lane >> 4, l15 = lane & 15;

  int bid = blockIdx.y * 32 + blockIdx.x;
  int sb  = (bid & 7) * 256 + (bid >> 3);      // XCD-bijective
  const int qt = 31 - (sb & 31);               // longest-first
  const int bh = sb >> 5;
  const int b  = bh >> 4, h = bh & 15;
  const long rowbase = (long)b * S_;

  bf16x8 qf[2];
  {
    const bf16_t* qp = qkv + (rowbase + qt * 64 + w * 16 + l15) * SQKV + h * DK_ + g * 8;
    qf[0] = *reinterpret_cast<const bf16x8*>(qp);
    qf[1] = *reinterpret_cast<const bf16x8*>(qp + 32);
  }
  float m_q = -1e30f, ssum = 0.f;
  f32x4 oacc[4] = {};                          // O^T[d = dc*16+g*4+j][q = l15]

  const bf16_t* kbase = qkv + rowbase * SQKV + D_ + h * DK_;
  const bf16_t* vbase = VT + (long)bh * 64 * S_;

  auto stageK = [&](int kvt, int buf) {
#pragma unroll
    for (int i = 0; i < 2; ++i) {
      int L = i * 256 + tid;
      int r = L >> 3, s = L & 7;
      int sc = s ^ (r & 7);
      gload_lds16(kbase + (long)(kvt * 64 + r) * SQKV + sc * 8,
                  ldsK[buf] + L * 16);
    }
  };
  auto stageV = [&](int kvt, int buf) {
#pragma unroll
    for (int i = 0; i < 2; ++i) {
      int L = i * 256 + tid;
      int r = L >> 3, s = L & 7;    // r = d row
      int sc = s ^ (r & 7);
      gload_lds16(vbase + (long)r * S_ + kvt * 64 + sc * 8,
                  ldsV[buf] + L * 16);
    }
  };

  stageK(0, 0); stageV(0, 0);                  // 4 VMEM ops in flight

  const int ql = w * 16 + l15;                 // this lane's q row (tile-local)
  const int gj = g * 4;                        // kv sub-offset from lane group

  for (int kvt = 0; kvt <= qt; ++kvt) {
    const int cur = kvt & 1;
    // own tile-kvt loads landed (issued a full compute-phase ago)
    asm volatile("s_waitcnt vmcnt(0)" ::: "memory");
    // rendezvous after the wait: all waves' tile-kvt in LDS; buf[cur^1] free
    __builtin_amdgcn_s_barrier();
    if (kvt < qt) { stageK(kvt + 1, cur ^ 1); stageV(kvt + 1, cur ^ 1); }

    // ---- S^T = K Q^T (scale + log2e folded into Wq) ----
    f32x4 sv[4];                               // sv[c][j]: kv = c*16+g*4+j, q = l15
    __builtin_amdgcn_s_setprio(1);
#pragma unroll
    for (int c = 0; c < 4; ++c) {
      f32x4 a = {};
#pragma unroll
      for (int kk = 0; kk < 2; ++kk) {
        int r = c * 16 + l15;
        int s = (kk * 4 + g) ^ (l15 & 7);
        bf16x8 kf = *reinterpret_cast<const bf16x8*>(ldsK[cur] + r * 128 + s * 16);
        a = __builtin_amdgcn_mfma_f32_16x16x32_bf16(kf, qf[kk], a, 0, 0, 0);
      }
      sv[c] = a;
    }
    __builtin_amdgcn_s_setprio(0);

    if (kvt == qt) {            // causal mask, diagonal tile only (uniform branch)
#pragma unroll
      for (int c = 0; c < 4; ++c)
#pragma unroll
        for (int j = 0; j < 4; ++j)
          if ((c * 16 + gj + j) > ql) sv[c][j] = -1e30f;
    }

    // ---- defer-max online softmax (log2 domain, q lane-local) ----
    float mxi = sv[0][0];
#pragma unroll
    for (int c = 0; c < 4; ++c)
#pragma unroll
      for (int j = 0; j < 4; ++j) mxi = fmaxf(mxi, sv[c][j]);
    if (__any(mxi > m_q + 8.0f)) {
      float mx = fmaxf(mxi, __shfl_xor(mxi, 16));
      mx = fmaxf(mx, __shfl_xor(mx, 32));      // reduce over g (4 lanes)
      float mn = fmaxf(m_q, mx);
      float al = fast_exp2(m_q - mn);
      m_q = mn;
      ssum *= al;
#pragma unroll
      for (int dc = 0; dc < 4; ++dc)
#pragma unroll
        for (int j = 0; j < 4; ++j) oacc[dc][j] *= al;
    }

    // ---- P^T = exp2(S^T - m) in-register -> PV B-frags directly ----
    bf16x8 pb[2];
#pragma unroll
    for (int ks = 0; ks < 2; ++ks)
#pragma unroll
      for (int half = 0; half < 2; ++half) {
        int c = ks * 2 + half;
#pragma unroll
        for (int j = 0; j < 4; ++j) {
          float p = fast_exp2(sv[c][j] - m_q);
          ssum += p;
          pb[ks][half * 4 + j] = (bf16_t)p;
        }
      }

    // ---- O^T += V^T P^T ----
    __builtin_amdgcn_s_setprio(1);
#pragma unroll
    for (int ks = 0; ks < 2; ++ks)
#pragma unroll
      for (int dc = 0; dc < 4; ++dc) {
        int r = dc * 16 + l15;
        int s = (ks * 4 + g) ^ (l15 & 7);
        bf16x8 vf = *reinterpret_cast<const bf16x8*>(ldsV[cur] + r * 128 + s * 16);
        oacc[dc] = __builtin_amdgcn_mfma_f32_16x16x32_bf16(vf, pb[ks], oacc[dc], 0, 0, 0);
      }
    __builtin_amdgcn_s_setprio(0);
  }

  // final: reduce ssum over g-lanes, normalize, write O (q = l15 row)
  ssum += __shfl_xor(ssum, 16);
  ssum += __shfl_xor(ssum, 32);
  float inv = 1.0f / ssum;
  long r = rowbase + qt * 64 + w * 16 + l15;
#pragma unroll
  for (int dc = 0; dc < 4; ++dc) {
    bf16x4 o;
#pragma unroll
    for (int j = 0; j < 4; ++j) o[j] = (bf16_t)(oacc[dc][j] * inv);
    *reinterpret_cast<bf16x4*>(&Ob[r * D_ + h * DK_ + dc * 16 + gj]) = o;
  }
}

// ---------------- launch ----------------
extern "C" void kernel_launch(void* const* d_in, const int* in_sizes, int n_in,
                              void* d_out, int out_size, void* d_ws, size_t ws_size,
                              hipStream_t stream) {
  const float* x  = (const float*)d_in[0];
  const float* Wq = (const float*)d_in[1];
  const float* Wk = (const float*)d_in[2];
  const float* Wv = (const float*)d_in[3];
  const float* Wo = (const float*)d_in[4];
  float* out = (float*)d_out;

  char* ws = (char*)d_ws;
  bf16_t* xb  = (bf16_t*)(ws);                    // [8192,1024]  (reused as VT later)
  bf16_t* Wc  = (bf16_t*)(ws + 16777216);         // [3072,1024]
  bf16_t* Wob = (bf16_t*)(ws + 23068672);         // [1024,1024]
  bf16_t* QKV = (bf16_t*)(ws + 25165824);         // [8192,3072]
  bf16_t* Ob  = (bf16_t*)(ws + 75497472);         // [8192,1024]
  bf16_t* VT  = xb;                               // [4096,2048] overlays dead xb

  const float QSCALE = 0.18033688f;               // 0.125 * log2(e)

  cast_f32_to_bf16<<<8192, 256, 0, stream>>>(x,  xb,            2097152, 1.0f);
  cast_f32_to_bf16<<<1024, 256, 0, stream>>>(Wq, Wc,             262144, QSCALE);
  cast_f32_to_bf16<<<1024, 256, 0, stream>>>(Wk, Wc + 1048576,   262144, 1.0f);
  cast_f32_to_bf16<<<1024, 256, 0, stream>>>(Wv, Wc + 2097152,   262144, 1.0f);
  cast_f32_to_bf16<<<1024, 256, 0, stream>>>(Wo, Wob,            262144, 1.0f);

  gemm_bt<bf16_t><<<dim3(24, 64), 256, 0, stream>>>(xb, Wc, QKV, 8192, 3072, 1024);
  vtrans_kernel<<<dim3(32, 64), 256, 0, stream>>>(QKV, VT);       // xb dead now
  attn_kernel<<<dim3(32, 64), 256, 0, stream>>>(QKV, VT, Ob);
  gemm_bt<float><<<dim3(8, 64), 256, 0, stream>>>(Ob, Wob, out, 8192, 1024, 1024);
}